// Round 7
// baseline (107.195 us; speedup 1.0000x reference)
//
#include <hip/hip_runtime.h>
#include <hip/hip_bf16.h>
#include <math.h>

// GAT layer B=8, N=2048, F=64 on gfx950.
// Round 7: k_attn stages B-tiles via __builtin_amdgcn_global_load_lds
// (async DMA -> LDS, zero VGPR cost): R3/R5 showed the compiler (VGPR 56/80)
// serializes register prefetch, exposing ~L2 latency per tile. Swizzled
// whswz layout is exactly the wave-uniform-base + lane*16B pattern glds needs.
// 4 waves = 2 i-groups x 2 j-parities; parity pair shares a double-buffered
// 8KB tile; P register-resident; one barrier/tile; LDS merge of i-group halves.

#define NN 2048
#define BB 8
#define ALPHA 0.2f

typedef __attribute__((ext_vector_type(8))) short s8v;   // 8 bf16 = 4 VGPRs
typedef __attribute__((ext_vector_type(4))) float f4v;

static __device__ __forceinline__ unsigned pk_bf16(float lo, float hi) {
  __hip_bfloat162 t = __float22bfloat162_rn(float2{lo, hi});
  return *(unsigned*)&t;
}

static __device__ __forceinline__ void glds16(const unsigned short* g,
                                              unsigned short* l) {
  __builtin_amdgcn_global_load_lds(
      (const __attribute__((address_space(1))) unsigned int*)g,
      (__attribute__((address_space(3))) unsigned int*)l, 16, 0, 0);
}

// ---------------- Kernel 1: adj -> 64-bit masks (unchanged from R6) ----------------
__global__ __launch_bounds__(256) void k_adj(const float* __restrict__ adj,
                                             unsigned long long* __restrict__ adjq) {
  const int t = threadIdx.x, lane = t & 63, w = t >> 6;
  const int row = blockIdx.x * 2 + (w >> 1);
  const int half = w & 1;
  const float* ar = adj + (size_t)row * NN + half * 1024;
  unsigned long long* aq = adjq + row * 32 + half * 16;
  #pragma unroll
  for (int it = 0; it < 16; ++it) {
    unsigned long long m = __ballot(ar[it * 64 + lane] > 0.f);
    if (lane == 0) aq[it] = m;
  }
}

// ---------------- Kernel 2: Wh -> swizzled bf16 + e1,e2 (unchanged from R6) ----------------
__global__ __launch_bounds__(256, 2) void k_wh(
    const float* __restrict__ h, const float* __restrict__ W,
    const float* __restrict__ a, unsigned short* __restrict__ whswz,
    float* __restrict__ e1, float* __restrict__ e2) {
  __shared__ __align__(16) float hs[32][68];
  const int t = threadIdx.x, lane = t & 63, w = t >> 6;
  const int rowBase = blockIdx.x * 32;
  const int b = rowBase >> 11, n0 = rowBase & (NN - 1);
  const int jt = n0 >> 6, ks = (n0 >> 5) & 1;

  float wr[64];
  #pragma unroll
  for (int k = 0; k < 16; ++k)
    *(f4v*)&wr[k * 4] = *(const f4v*)&W[lane * 64 + k * 4];

  #pragma unroll
  for (int qq = 0; qq < 2; ++qq) {
    const int idx = t + 256 * qq;
    const int r = idx >> 4, c = (idx & 15) * 4;
    *(f4v*)&hs[r][c] = *(const f4v*)&h[(size_t)(rowBase + r) * 64 + c];
  }
  const float a1v = a[lane], a2v = a[64 + lane];
  __syncthreads();

  const int r0 = w * 8;
  float acc[8];
  #pragma unroll
  for (int rr = 0; rr < 8; ++rr) acc[rr] = 0.f;
  #pragma unroll
  for (int f4i = 0; f4i < 16; ++f4i) {
    f4v hv[8];
    #pragma unroll
    for (int rr = 0; rr < 8; ++rr)
      hv[rr] = *(const f4v*)&hs[r0 + rr][f4i * 4];
    #pragma unroll
    for (int x = 0; x < 4; ++x) {
      const float wv = wr[f4i * 4 + x];
      #pragma unroll
      for (int rr = 0; rr < 8; ++rr) acc[rr] = fmaf(hv[rr][x], wv, acc[rr]);
    }
  }

  {
    union { s8v v; unsigned u[4]; } cv;
    cv.u[0] = pk_bf16(acc[0], acc[1]);
    cv.u[1] = pk_bf16(acc[2], acc[3]);
    cv.u[2] = pk_bf16(acc[4], acc[5]);
    cv.u[3] = pk_bf16(acc[6], acc[7]);
    unsigned short* dst = whswz + ((size_t)b << 17) + (jt << 12) +
                          ((((lane >> 4) << 1) + ks) << 9) +
                          ((w * 16 + (lane & 15)) << 3);
    *(s8v*)dst = cv.v;
  }

  float s1[8], s2[8];
  #pragma unroll
  for (int rr = 0; rr < 8; ++rr) { s1[rr] = acc[rr] * a1v; s2[rr] = acc[rr] * a2v; }
  #pragma unroll
  for (int m = 1; m < 64; m <<= 1)
    #pragma unroll
    for (int rr = 0; rr < 8; ++rr) {
      s1[rr] += __shfl_xor(s1[rr], m);
      s2[rr] += __shfl_xor(s2[rr], m);
    }
  if (lane == 0)
    #pragma unroll
    for (int rr = 0; rr < 8; ++rr) {
      e1[rowBase + r0 + rr] = s1[rr];
      e2[rowBase + r0 + rr] = s2[rr];
    }
}

// ---------------- Kernel 3: fused attention, async-LDS staging ----------------
// Grid (N/32, B) = (64, 8) = 512 blocks, 256 thr (4 waves).
// Wave w: i-group ig=w>>1 (16 rows), j-parity jp=w&1 (16 tiles).
// Parity pair {jp, 2+jp} stages tile jt into tile[jp][buf] (glds, 4/wave),
// double-buffered, one barrier per tile. P in registers; pair-merge via LDS.
__global__ __launch_bounds__(256, 2) void k_attn(
    const unsigned long long* __restrict__ adjq,
    const unsigned short* __restrict__ whswz,
    const float* __restrict__ e1g, const float* __restrict__ e2g,
    float* __restrict__ out) {
  __shared__ __align__(16) unsigned short tile[2][2][4096];  // [par][buf] 32 KB
  __shared__ __align__(16) float e2row[NN];                  //  8 KB
  __shared__ __align__(16) float pc[2][16][68];              //  8.7 KB
  __shared__ float ls[2][16];

  const int t = threadIdx.x, lane = t & 63, w = t >> 6;
  const int q = lane >> 4, l15 = lane & 15;
  const int ig = w >> 1, jp = w & 1;     // i-group, j-parity (half = ig)
  const int b = blockIdx.y;
  const int i0 = blockIdx.x * 32;
  const size_t bN = (size_t)b * NN;

  // stage full e2 row for this batch
  #pragma unroll
  for (int kk = 0; kk < 2; ++kk) {
    const int idx = (t + 256 * kk) * 4;
    *(f4v*)&e2row[idx] = *(const f4v*)&e2g[bN + idx];
  }

  const int iw0 = i0 + ig * 16;
  const float e1v = e1g[bN + iw0 + l15];
  const unsigned long long* arow = adjq + (size_t)(iw0 + l15) * 32;
  const unsigned short* src = whswz + ((size_t)b << 17);

  // async stage: this wave covers half `ig` of tile jt (4 x 1KB glds)
  auto stage = [&](int buf, int jt) {
    const unsigned short* g = src + (jt << 12) + (ig << 11) + (lane << 3);
    #pragma unroll
    for (int ins = 0; ins < 4; ++ins)
      glds16(g + ins * 512, &tile[jp][buf][(ig << 11) + ins * 512]);
  };

  f4v acc[4];
  #pragma unroll
  for (int s = 0; s < 4; ++s) acc[s] = f4v{0.f, 0.f, 0.f, 0.f};
  float psum = 0.f;

  stage(0, jp);
  __syncthreads();          // tile 0 staged + e2row visible

  #pragma unroll 4
  for (int k = 0; k < 16; ++k) {
    const int buf = k & 1;
    const int jt = 2 * k + jp;
    if (k < 15) stage(buf ^ 1, 2 * (k + 1) + jp);   // async prefetch, no regs

    // P-gen in registers (thread owns A[m=l15][k=q*8+jj])
    const unsigned long long amc = arow[jt];
    const int j0 = jt << 6;
    s8v af[2];
    #pragma unroll
    for (int ks = 0; ks < 2; ++ks) {
      const unsigned bits = (unsigned)(amc >> (ks * 32 + q * 8)) & 0xffu;
      const f4v ea = *(const f4v*)&e2row[j0 + ks * 32 + q * 8];
      const f4v eb = *(const f4v*)&e2row[j0 + ks * 32 + q * 8 + 4];
      float p[8];
      #pragma unroll
      for (int jj = 0; jj < 8; ++jj) {
        const float s = e1v + (jj < 4 ? ea[jj & 3] : eb[jj & 3]);
        const float lr = fmaxf(s, ALPHA * s);
        const float pv = ((bits >> jj) & 1u) ? __expf(lr) : 0.f;
        p[jj] = pv;
        psum += pv;
      }
      union { s8v v; unsigned u[4]; } cv;
      cv.u[0] = pk_bf16(p[0], p[1]);
      cv.u[1] = pk_bf16(p[2], p[3]);
      cv.u[2] = pk_bf16(p[4], p[5]);
      cv.u[3] = pk_bf16(p[6], p[7]);
      af[ks] = cv.v;
    }

    // B-frags from LDS (ds_read_b128, conflict-free) + MFMA
    #pragma unroll
    for (int s = 0; s < 4; ++s) {
      const s8v b0 = *(const s8v*)&tile[jp][buf][((s * 2 + 0) << 9) + (lane << 3)];
      const s8v b1 = *(const s8v*)&tile[jp][buf][((s * 2 + 1) << 9) + (lane << 3)];
      acc[s] = __builtin_amdgcn_mfma_f32_16x16x32_bf16(af[0], b0, acc[s], 0, 0, 0);
      acc[s] = __builtin_amdgcn_mfma_f32_16x16x32_bf16(af[1], b1, acc[s], 0, 0, 0);
    }
    __syncthreads();        // next tile staged; buf consumable for reuse
  }

  // wave-local rowsum over q-strips (this wave's j-parity subset)
  psum += __shfl_xor(psum, 16);
  psum += __shfl_xor(psum, 32);

  // parity-1 waves publish partials; parity-0 waves merge + epilogue
  if (jp == 1) {
    if (lane < 16) ls[ig][lane] = psum;
    #pragma unroll
    for (int s = 0; s < 4; ++s)
      #pragma unroll
      for (int r = 0; r < 4; ++r)
        pc[ig][q * 4 + r][s * 16 + l15] = acc[s][r];
  }
  __syncthreads();
  if (jp == 0) {
    float rs[4];
    #pragma unroll
    for (int r = 0; r < 4; ++r)
      rs[r] = __shfl(psum, q * 4 + r) + ls[ig][q * 4 + r];
    #pragma unroll
    for (int s = 0; s < 4; ++s)
      #pragma unroll
      for (int r = 0; r < 4; ++r) {
        float v = (acc[s][r] + pc[ig][q * 4 + r][s * 16 + l15]) / rs[r];
        v = v > 0.f ? v : expm1f(v);
        out[(bN + iw0 + q * 4 + r) * 64 + s * 16 + l15] = v;
      }
  }
}

extern "C" void kernel_launch(void* const* d_in, const int* in_sizes, int n_in,
                              void* d_out, int out_size, void* d_ws, size_t ws_size,
                              hipStream_t stream) {
  (void)in_sizes; (void)n_in; (void)out_size; (void)ws_size;
  const float* h   = (const float*)d_in[0];
  const float* adj = (const float*)d_in[1];
  const float* W   = (const float*)d_in[2];
  const float* a   = (const float*)d_in[3];
  float* outp = (float*)d_out;

  // ws carve: whswz 2 MB | e1 64 KB | e2 64 KB | adjq 512 KB
  unsigned short* whswz = (unsigned short*)d_ws;
  float* e1 = (float*)((char*)d_ws + (size_t)BB * 64 * NN * 2);
  float* e2 = e1 + (size_t)BB * NN;
  unsigned long long* adjq = (unsigned long long*)(e2 + (size_t)BB * NN);

  k_adj<<<NN / 2, 256, 0, stream>>>(adj, adjq);
  k_wh<<<(BB * NN) / 32, 256, 0, stream>>>(h, W, a, whswz, e1, e2);
  k_attn<<<dim3(NN / 32, BB), 256, 0, stream>>>(adjq, whswz, e1, e2, outp);
}

// Round 8
// 99.610 us; speedup vs baseline: 1.0761x; 1.0761x over previous
//
#include <hip/hip_runtime.h>
#include <hip/hip_bf16.h>
#include <math.h>

// GAT layer B=8, N=2048, F=64 on gfx950.
// Round 8: (1) k_attn two independent chains per wave (tiles k, k+4) --
// 16 loads issue at body top, two load-independent P-gens (~500 cyc) fill
// the L2 latency window, MFMAs consume at body bottom; no barriers in loop.
// (2) exp() hoisted out of inner loop via factorization:
//     exp(lrelu(e1+e2)) = (E1p*E2p > 1) ? E1p*E2p : E1n*E2n,
//     E?p=exp(e), E?n=exp(0.2e) precomputed in k_pre. Inner j: 7 VALU, no exp.
// (3) k_adj fused into k_pre (parallel block ranges) -- one less dispatch.

#define NN 2048
#define BB 8

typedef __attribute__((ext_vector_type(8))) short s8v;   // 8 bf16 = 4 VGPRs
typedef __attribute__((ext_vector_type(4))) float f4v;

static __device__ __forceinline__ unsigned pk_bf16(float lo, float hi) {
  __hip_bfloat162 t = __float22bfloat162_rn(float2{lo, hi});
  return *(unsigned*)&t;
}

// ---------------- Kernel 1: Wh/e-factors (blocks 0..511) + adj masks (512..1535) ----------------
__global__ __launch_bounds__(256, 2) void k_pre(
    const float* __restrict__ adj, const float* __restrict__ h,
    const float* __restrict__ W, const float* __restrict__ a,
    unsigned long long* __restrict__ adjq, unsigned short* __restrict__ whswz,
    float2* __restrict__ e1pn, float2* __restrict__ e2pn) {
  const int t = threadIdx.x, lane = t & 63, w = t >> 6;

  if (blockIdx.x >= 512) {
    // ---- adj -> bit rows: 2 rows/block, wave -> half row, 16 ballots ----
    const int bid = blockIdx.x - 512;
    const int row = bid * 2 + (w >> 1);
    const int half = w & 1;
    const float* ar = adj + (size_t)row * NN + half * 1024;
    unsigned long long* aq = adjq + row * 32 + half * 16;
    #pragma unroll
    for (int it = 0; it < 16; ++it) {
      unsigned long long m = __ballot(ar[it * 64 + lane] > 0.f);
      if (lane == 0) aq[it] = m;
    }
    return;
  }

  // ---- Wh (bf16, swizzled) + e-factor computation; 32 n-rows/block ----
  __shared__ __align__(16) float hs[32][68];
  const int rowBase = blockIdx.x * 32;
  const int b = rowBase >> 11, n0 = rowBase & (NN - 1);
  const int jt = n0 >> 6, ks = (n0 >> 5) & 1;

  float wr[64];                                  // W row `lane` (o = lane)
  #pragma unroll
  for (int k = 0; k < 16; ++k)
    *(f4v*)&wr[k * 4] = *(const f4v*)&W[lane * 64 + k * 4];

  #pragma unroll
  for (int qq = 0; qq < 2; ++qq) {
    const int idx = t + 256 * qq;
    const int r = idx >> 4, c = (idx & 15) * 4;
    *(f4v*)&hs[r][c] = *(const f4v*)&h[(size_t)(rowBase + r) * 64 + c];
  }
  const float a1v = a[lane], a2v = a[64 + lane];
  __syncthreads();

  const int r0 = w * 8;
  float acc[8];
  #pragma unroll
  for (int rr = 0; rr < 8; ++rr) acc[rr] = 0.f;
  #pragma unroll
  for (int f4i = 0; f4i < 16; ++f4i) {
    f4v hv[8];
    #pragma unroll
    for (int rr = 0; rr < 8; ++rr)
      hv[rr] = *(const f4v*)&hs[r0 + rr][f4i * 4];       // lane-uniform broadcast
    #pragma unroll
    for (int x = 0; x < 4; ++x) {
      const float wv = wr[f4i * 4 + x];
      #pragma unroll
      for (int rr = 0; rr < 8; ++rr) acc[rr] = fmaf(hv[rr][x], wv, acc[rr]);
    }
  }

  {  // swizzled store straight from registers (16B/thread)
    union { s8v v; unsigned u[4]; } cv;
    cv.u[0] = pk_bf16(acc[0], acc[1]);
    cv.u[1] = pk_bf16(acc[2], acc[3]);
    cv.u[2] = pk_bf16(acc[4], acc[5]);
    cv.u[3] = pk_bf16(acc[6], acc[7]);
    unsigned short* dst = whswz + ((size_t)b << 17) + (jt << 12) +
                          ((((lane >> 4) << 1) + ks) << 9) +
                          ((w * 16 + (lane & 15)) << 3);
    *(s8v*)dst = cv.v;
  }

  float s1[8], s2[8];
  #pragma unroll
  for (int rr = 0; rr < 8; ++rr) { s1[rr] = acc[rr] * a1v; s2[rr] = acc[rr] * a2v; }
  #pragma unroll
  for (int m = 1; m < 64; m <<= 1)
    #pragma unroll
    for (int rr = 0; rr < 8; ++rr) {
      s1[rr] += __shfl_xor(s1[rr], m);
      s2[rr] += __shfl_xor(s2[rr], m);
    }
  // all lanes hold totals; compute factors wave-wide, lane 0 stores
  #pragma unroll
  for (int rr = 0; rr < 8; ++rr) {
    const float2 f1 = {__expf(s1[rr]), __expf(0.2f * s1[rr])};
    const float2 f2 = {__expf(s2[rr]), __expf(0.2f * s2[rr])};
    if (lane == 0) {
      e1pn[rowBase + r0 + rr] = f1;
      e2pn[rowBase + r0 + rr] = f2;
    }
  }
}

// ---------------- Kernel 2: fused attention, two-chain ----------------
// Grid (N/16, B) = (128, 8), 256 thr (4 waves). Wave w = j-quarter w.
// Body k=0..3: chains A (tile w*8+k) and B (tile w*8+4+k): 16 loads at top,
// two load-independent P-gens in the middle, 16 MFMAs at bottom.
__global__ __launch_bounds__(256, 4) void k_attn(
    const unsigned long long* __restrict__ adjq,
    const unsigned short* __restrict__ whswz,
    const float2* __restrict__ e1png, const float2* __restrict__ e2png,
    float* __restrict__ out) {
  __shared__ __align__(16) float2 e2s[NN];        // 16 KB {E2p,E2n} per j
  __shared__ __align__(16) float pc[4][16][68];   // 17.4 KB
  __shared__ float ls[4][16];

  const int t = threadIdx.x, lane = t & 63, w = t >> 6;
  const int q = lane >> 4, l15 = lane & 15;
  const int b = blockIdx.y;
  const int i0 = blockIdx.x * 16;
  const size_t bN = (size_t)b * NN;

  // stage e2 factors (4 x f4v = 2 float2s each per thread)
  #pragma unroll
  for (int kk = 0; kk < 4; ++kk) {
    const int idx4 = t + 256 * kk;                // 1024 f4v chunks
    ((f4v*)e2s)[idx4] = ((const f4v*)(e2png + bN))[idx4];
  }

  const float2 e1f = e1png[bN + i0 + l15];
  const float E1p = e1f.x, E1n = e1f.y;
  const unsigned long long* arow = adjq + (size_t)(i0 + l15) * 32 + w * 8;
  const unsigned short* tb = whswz + ((size_t)b << 17) + ((size_t)(w * 8) << 12);

  f4v accA[4], accB[4];
  #pragma unroll
  for (int s = 0; s < 4; ++s) {
    accA[s] = f4v{0.f, 0.f, 0.f, 0.f};
    accB[s] = f4v{0.f, 0.f, 0.f, 0.f};
  }
  float psum = 0.f;

  __syncthreads();   // e2s visible

  #pragma unroll
  for (int k = 0; k < 4; ++k) {
    // ---- load phase: both chains' B-fragments + adj words ----
    s8v bfA[8], bfB[8];
    const unsigned short* gA = tb + (k << 12) + (lane << 3);
    const unsigned short* gB = gA + (4 << 12);
    #pragma unroll
    for (int f = 0; f < 8; ++f) {
      bfA[f] = *(const s8v*)(gA + (f << 9));
      bfB[f] = *(const s8v*)(gB + (f << 9));
    }
    const unsigned long long amA = arow[k], amB = arow[k + 4];

    // ---- P-gen phase (depends only on LDS e2s; fills load latency) ----
    s8v afA[2], afB[2];
    #pragma unroll
    for (int ch = 0; ch < 2; ++ch) {
      const unsigned long long am = ch ? amB : amA;
      const int j0 = (w * 8 + k + (ch ? 4 : 0)) << 6;
      #pragma unroll
      for (int ks = 0; ks < 2; ++ks) {
        const unsigned bits = (unsigned)(am >> (ks * 32 + q * 8)) & 0xffu;
        const int jb = j0 + ks * 32 + q * 8;
        float p[8];
        #pragma unroll
        for (int jj = 0; jj < 8; ++jj) {
          const float2 e2f = e2s[jb + jj];
          const float mp = E1p * e2f.x;          // exp(e1+e2)
          const float mn = E1n * e2f.y;          // exp(0.2*(e1+e2))
          float pv = mp > 1.f ? mp : mn;         // leaky-relu in exp domain
          pv = ((bits >> jj) & 1u) ? pv : 0.f;
          p[jj] = pv;
          psum += pv;
        }
        union { s8v v; unsigned u[4]; } cv;
        cv.u[0] = pk_bf16(p[0], p[1]);
        cv.u[1] = pk_bf16(p[2], p[3]);
        cv.u[2] = pk_bf16(p[4], p[5]);
        cv.u[3] = pk_bf16(p[6], p[7]);
        if (ch) afB[ks] = cv.v; else afA[ks] = cv.v;
      }
    }

    // ---- MFMA phase ----
    #pragma unroll
    for (int s = 0; s < 4; ++s) {
      accA[s] = __builtin_amdgcn_mfma_f32_16x16x32_bf16(afA[0], bfA[s * 2 + 0], accA[s], 0, 0, 0);
      accA[s] = __builtin_amdgcn_mfma_f32_16x16x32_bf16(afA[1], bfA[s * 2 + 1], accA[s], 0, 0, 0);
      accB[s] = __builtin_amdgcn_mfma_f32_16x16x32_bf16(afB[0], bfB[s * 2 + 0], accB[s], 0, 0, 0);
      accB[s] = __builtin_amdgcn_mfma_f32_16x16x32_bf16(afB[1], bfB[s * 2 + 1], accB[s], 0, 0, 0);
    }
  }

  // merge chains; wave-local rowsum; stash partials
  f4v acc[4];
  #pragma unroll
  for (int s = 0; s < 4; ++s) acc[s] = accA[s] + accB[s];
  psum += __shfl_xor(psum, 16);
  psum += __shfl_xor(psum, 32);
  if (lane < 16) ls[w][lane] = psum;
  #pragma unroll
  for (int s = 0; s < 4; ++s)
    #pragma unroll
    for (int r = 0; r < 4; ++r)
      pc[w][q * 4 + r][s * 16 + l15] = acc[s][r];
  __syncthreads();

  // cross-wave j-reduction + epilogue: thread t -> row t>>4, 4 cols
  const int row = t >> 4, c0 = (t & 15) * 4;
  f4v sum = *(const f4v*)&pc[0][row][c0];
  #pragma unroll
  for (int j = 1; j < 4; ++j) sum += *(const f4v*)&pc[j][row][c0];
  const float rsum = ls[0][row] + ls[1][row] + ls[2][row] + ls[3][row];
  f4v o;
  #pragma unroll
  for (int x = 0; x < 4; ++x) {
    float v = sum[x] / rsum;
    o[x] = v > 0.f ? v : expm1f(v);
  }
  *(f4v*)&out[(bN + i0 + row) * 64 + c0] = o;
}

extern "C" void kernel_launch(void* const* d_in, const int* in_sizes, int n_in,
                              void* d_out, int out_size, void* d_ws, size_t ws_size,
                              hipStream_t stream) {
  (void)in_sizes; (void)n_in; (void)out_size; (void)ws_size;
  const float* h   = (const float*)d_in[0];
  const float* adj = (const float*)d_in[1];
  const float* W   = (const float*)d_in[2];
  const float* a   = (const float*)d_in[3];
  float* outp = (float*)d_out;

  // ws carve: whswz 2 MB | e1pn 128 KB | e2pn 128 KB | adjq 512 KB
  unsigned short* whswz = (unsigned short*)d_ws;
  float2* e1pn = (float2*)((char*)d_ws + (size_t)BB * 64 * NN * 2);
  float2* e2pn = e1pn + (size_t)BB * NN;
  unsigned long long* adjq = (unsigned long long*)(e2pn + (size_t)BB * NN);

  k_pre<<<1536, 256, 0, stream>>>(adj, h, W, a, adjq, whswz, e1pn, e2pn);
  k_attn<<<dim3(NN / 16, BB), 256, 0, stream>>>(adjq, whswz, e1pn, e2pn, outp);
}

// Round 9
// 98.503 us; speedup vs baseline: 1.0882x; 1.0112x over previous
//
#include <hip/hip_runtime.h>
#include <hip/hip_bf16.h>
#include <math.h>

// GAT layer B=8, N=2048, F=64 on gfx950.
// Round 9 = Round 8 + XCD/CU-aware block swizzle in k_attn:
//   g = linear block id; b = g&7 -> XCD g%8 serves ONLY batch b (256KB
//   whswz[b] pinned in that XCD's 4MB L2); itile = ((g&255)>>3)*4 + (g>>8)
//   -> the 4 co-resident blocks per CU (g, g+256, g+512, g+768) share b and
//   stream the same tiles in order => ~4x L1 reuse on B-fragments.
// Plus: e2s inner reads as ds_read_b128 (was b64), halving LDS instrs.

#define NN 2048
#define BB 8

typedef __attribute__((ext_vector_type(8))) short s8v;   // 8 bf16 = 4 VGPRs
typedef __attribute__((ext_vector_type(4))) float f4v;

static __device__ __forceinline__ unsigned pk_bf16(float lo, float hi) {
  __hip_bfloat162 t = __float22bfloat162_rn(float2{lo, hi});
  return *(unsigned*)&t;
}

// ---------------- Kernel 1: Wh/e-factors (blocks 0..511) + adj masks (512..1535) ----------------
__global__ __launch_bounds__(256, 2) void k_pre(
    const float* __restrict__ adj, const float* __restrict__ h,
    const float* __restrict__ W, const float* __restrict__ a,
    unsigned long long* __restrict__ adjq, unsigned short* __restrict__ whswz,
    float2* __restrict__ e1pn, float2* __restrict__ e2pn) {
  const int t = threadIdx.x, lane = t & 63, w = t >> 6;

  if (blockIdx.x >= 512) {
    // ---- adj -> bit rows: 2 rows/block, wave -> half row, 16 ballots ----
    const int bid = blockIdx.x - 512;
    const int row = bid * 2 + (w >> 1);
    const int half = w & 1;
    const float* ar = adj + (size_t)row * NN + half * 1024;
    unsigned long long* aq = adjq + row * 32 + half * 16;
    #pragma unroll
    for (int it = 0; it < 16; ++it) {
      unsigned long long m = __ballot(ar[it * 64 + lane] > 0.f);
      if (lane == 0) aq[it] = m;
    }
    return;
  }

  // ---- Wh (bf16, swizzled) + e-factors; 32 n-rows/block ----
  __shared__ __align__(16) float hs[32][68];
  const int rowBase = blockIdx.x * 32;
  const int b = rowBase >> 11, n0 = rowBase & (NN - 1);
  const int jt = n0 >> 6, ks = (n0 >> 5) & 1;

  float wr[64];                                  // W row `lane` (o = lane)
  #pragma unroll
  for (int k = 0; k < 16; ++k)
    *(f4v*)&wr[k * 4] = *(const f4v*)&W[lane * 64 + k * 4];

  #pragma unroll
  for (int qq = 0; qq < 2; ++qq) {
    const int idx = t + 256 * qq;
    const int r = idx >> 4, c = (idx & 15) * 4;
    *(f4v*)&hs[r][c] = *(const f4v*)&h[(size_t)(rowBase + r) * 64 + c];
  }
  const float a1v = a[lane], a2v = a[64 + lane];
  __syncthreads();

  const int r0 = w * 8;
  float acc[8];
  #pragma unroll
  for (int rr = 0; rr < 8; ++rr) acc[rr] = 0.f;
  #pragma unroll
  for (int f4i = 0; f4i < 16; ++f4i) {
    f4v hv[8];
    #pragma unroll
    for (int rr = 0; rr < 8; ++rr)
      hv[rr] = *(const f4v*)&hs[r0 + rr][f4i * 4];       // lane-uniform broadcast
    #pragma unroll
    for (int x = 0; x < 4; ++x) {
      const float wv = wr[f4i * 4 + x];
      #pragma unroll
      for (int rr = 0; rr < 8; ++rr) acc[rr] = fmaf(hv[rr][x], wv, acc[rr]);
    }
  }

  {  // swizzled store straight from registers (16B/thread)
    union { s8v v; unsigned u[4]; } cv;
    cv.u[0] = pk_bf16(acc[0], acc[1]);
    cv.u[1] = pk_bf16(acc[2], acc[3]);
    cv.u[2] = pk_bf16(acc[4], acc[5]);
    cv.u[3] = pk_bf16(acc[6], acc[7]);
    unsigned short* dst = whswz + ((size_t)b << 17) + (jt << 12) +
                          ((((lane >> 4) << 1) + ks) << 9) +
                          ((w * 16 + (lane & 15)) << 3);
    *(s8v*)dst = cv.v;
  }

  float s1[8], s2[8];
  #pragma unroll
  for (int rr = 0; rr < 8; ++rr) { s1[rr] = acc[rr] * a1v; s2[rr] = acc[rr] * a2v; }
  #pragma unroll
  for (int m = 1; m < 64; m <<= 1)
    #pragma unroll
    for (int rr = 0; rr < 8; ++rr) {
      s1[rr] += __shfl_xor(s1[rr], m);
      s2[rr] += __shfl_xor(s2[rr], m);
    }
  #pragma unroll
  for (int rr = 0; rr < 8; ++rr) {
    const float2 f1 = {__expf(s1[rr]), __expf(0.2f * s1[rr])};
    const float2 f2 = {__expf(s2[rr]), __expf(0.2f * s2[rr])};
    if (lane == 0) {
      e1pn[rowBase + r0 + rr] = f1;
      e2pn[rowBase + r0 + rr] = f2;
    }
  }
}

// ---------------- Kernel 2: fused attention, two-chain + XCD swizzle ----------------
// 1024 blocks x 256 thr (4 waves). b = g&7 (XCD-pinned), itile contiguous
// across the 4 co-resident blocks per CU. Wave w = j-quarter w; body k=0..3
// runs chains A (tile w*8+k) and B (tile w*8+4+k).
__global__ __launch_bounds__(256, 4) void k_attn(
    const unsigned long long* __restrict__ adjq,
    const unsigned short* __restrict__ whswz,
    const float2* __restrict__ e1png, const float2* __restrict__ e2png,
    float* __restrict__ out) {
  __shared__ __align__(16) float2 e2s[NN];        // 16 KB {E2p,E2n} per j
  __shared__ __align__(16) float pc[4][16][68];   // 17.4 KB
  __shared__ float ls[4][16];

  const int t = threadIdx.x, lane = t & 63, w = t >> 6;
  const int q = lane >> 4, l15 = lane & 15;
  // swizzle: XCD g%8 -> batch b; co-resident blocks get contiguous itile
  const int g = blockIdx.x;
  const int b = g & 7;
  const int itile = (((g & 255) >> 3) << 2) + (g >> 8);
  const int i0 = itile * 16;
  const size_t bN = (size_t)b * NN;

  // stage e2 factors (1024 f4v chunks)
  #pragma unroll
  for (int kk = 0; kk < 4; ++kk) {
    const int idx4 = t + 256 * kk;
    ((f4v*)e2s)[idx4] = ((const f4v*)(e2png + bN))[idx4];
  }

  const float2 e1f = e1png[bN + i0 + l15];
  const float E1p = e1f.x, E1n = e1f.y;
  const unsigned long long* arow = adjq + (size_t)(i0 + l15) * 32 + w * 8;
  const unsigned short* tb = whswz + ((size_t)b << 17) + ((size_t)(w * 8) << 12);

  f4v accA[4], accB[4];
  #pragma unroll
  for (int s = 0; s < 4; ++s) {
    accA[s] = f4v{0.f, 0.f, 0.f, 0.f};
    accB[s] = f4v{0.f, 0.f, 0.f, 0.f};
  }
  float psum = 0.f;

  __syncthreads();   // e2s visible

  #pragma unroll
  for (int k = 0; k < 4; ++k) {
    // ---- load phase: both chains' B-fragments + adj words ----
    s8v bfA[8], bfB[8];
    const unsigned short* gA = tb + (k << 12) + (lane << 3);
    const unsigned short* gB = gA + (4 << 12);
    #pragma unroll
    for (int f = 0; f < 8; ++f) {
      bfA[f] = *(const s8v*)(gA + (f << 9));
      bfB[f] = *(const s8v*)(gB + (f << 9));
    }
    const unsigned long long amA = arow[k], amB = arow[k + 4];

    // ---- P-gen phase (LDS-only deps; fills load latency) ----
    s8v afA[2], afB[2];
    #pragma unroll
    for (int ch = 0; ch < 2; ++ch) {
      const unsigned long long am = ch ? amB : amA;
      const int j0 = (w * 8 + k + (ch ? 4 : 0)) << 6;
      #pragma unroll
      for (int ks = 0; ks < 2; ++ks) {
        const unsigned bits = (unsigned)(am >> (ks * 32 + q * 8)) & 0xffu;
        const int jb = j0 + ks * 32 + q * 8;
        // 4 x b128 reads cover {E2p,E2n} for 8 j's (broadcast across l15)
        f4v ev[4];
        #pragma unroll
        for (int x = 0; x < 4; ++x)
          ev[x] = *(const f4v*)((const float*)e2s + 2 * jb + 4 * x);
        float p[8];
        #pragma unroll
        for (int jj = 0; jj < 8; ++jj) {
          const float p2 = ev[jj >> 1][(jj & 1) << 1];
          const float n2 = ev[jj >> 1][((jj & 1) << 1) + 1];
          const float mp = E1p * p2;             // exp(e1+e2)
          const float mn = E1n * n2;             // exp(0.2*(e1+e2))
          float pv = mp > 1.f ? mp : mn;         // leaky-relu in exp domain
          pv = ((bits >> jj) & 1u) ? pv : 0.f;
          p[jj] = pv;
          psum += pv;
        }
        union { s8v v; unsigned u[4]; } cv;
        cv.u[0] = pk_bf16(p[0], p[1]);
        cv.u[1] = pk_bf16(p[2], p[3]);
        cv.u[2] = pk_bf16(p[4], p[5]);
        cv.u[3] = pk_bf16(p[6], p[7]);
        if (ch) afB[ks] = cv.v; else afA[ks] = cv.v;
      }
    }

    // ---- MFMA phase ----
    #pragma unroll
    for (int s = 0; s < 4; ++s) {
      accA[s] = __builtin_amdgcn_mfma_f32_16x16x32_bf16(afA[0], bfA[s * 2 + 0], accA[s], 0, 0, 0);
      accA[s] = __builtin_amdgcn_mfma_f32_16x16x32_bf16(afA[1], bfA[s * 2 + 1], accA[s], 0, 0, 0);
      accB[s] = __builtin_amdgcn_mfma_f32_16x16x32_bf16(afB[0], bfB[s * 2 + 0], accB[s], 0, 0, 0);
      accB[s] = __builtin_amdgcn_mfma_f32_16x16x32_bf16(afB[1], bfB[s * 2 + 1], accB[s], 0, 0, 0);
    }
  }

  // merge chains; wave-local rowsum; stash partials
  f4v acc[4];
  #pragma unroll
  for (int s = 0; s < 4; ++s) acc[s] = accA[s] + accB[s];
  psum += __shfl_xor(psum, 16);
  psum += __shfl_xor(psum, 32);
  if (lane < 16) ls[w][lane] = psum;
  #pragma unroll
  for (int s = 0; s < 4; ++s)
    #pragma unroll
    for (int r = 0; r < 4; ++r)
      pc[w][q * 4 + r][s * 16 + l15] = acc[s][r];
  __syncthreads();

  // cross-wave j-reduction + epilogue: thread t -> row t>>4, 4 cols
  const int row = t >> 4, c0 = (t & 15) * 4;
  f4v sum = *(const f4v*)&pc[0][row][c0];
  #pragma unroll
  for (int j = 1; j < 4; ++j) sum += *(const f4v*)&pc[j][row][c0];
  const float rsum = ls[0][row] + ls[1][row] + ls[2][row] + ls[3][row];
  f4v o;
  #pragma unroll
  for (int x = 0; x < 4; ++x) {
    float v = sum[x] / rsum;
    o[x] = v > 0.f ? v : expm1f(v);
  }
  *(f4v*)&out[(bN + i0 + row) * 64 + c0] = o;
}

extern "C" void kernel_launch(void* const* d_in, const int* in_sizes, int n_in,
                              void* d_out, int out_size, void* d_ws, size_t ws_size,
                              hipStream_t stream) {
  (void)in_sizes; (void)n_in; (void)out_size; (void)ws_size;
  const float* h   = (const float*)d_in[0];
  const float* adj = (const float*)d_in[1];
  const float* W   = (const float*)d_in[2];
  const float* a   = (const float*)d_in[3];
  float* outp = (float*)d_out;

  // ws carve: whswz 2 MB | e1pn 128 KB | e2pn 128 KB | adjq 512 KB
  unsigned short* whswz = (unsigned short*)d_ws;
  float2* e1pn = (float2*)((char*)d_ws + (size_t)BB * 64 * NN * 2);
  float2* e2pn = e1pn + (size_t)BB * NN;
  unsigned long long* adjq = (unsigned long long*)(e2pn + (size_t)BB * NN);

  k_pre<<<1536, 256, 0, stream>>>(adj, h, W, a, adjq, whswz, e1pn, e2pn);
  k_attn<<<BB * (NN / 16), 256, 0, stream>>>(adjq, whswz, e1pn, e2pn, outp);
}

// Round 10
// 97.882 us; speedup vs baseline: 1.0951x; 1.0063x over previous
//
#include <hip/hip_runtime.h>
#include <hip/hip_bf16.h>
#include <math.h>

// GAT layer B=8, N=2048, F=64 on gfx950.
// Round 10: PV GEMM on mfma_f32_32x32x16_bf16 (B-frag bytes/FLOP and MFMA
// instr count halve vs 16x16x32; B reused across 32 i-rows). P register-
// resident via A-layout m=lane&31, k=(lane>>5)*8+e (generalized from the
// R2-R9-proven 16x16 mapping). e2 factors packed {bf16(exp),bf16(exp0.2)}
// in one dword (k_pre pre-packs) -> LDS reads halve. pc-reduce LDS aliased
// over e2 buffer; 512 blocks x 512 thr, XCD-pinned b=g&7, 2 blocks/CU.

#define NN 2048
#define BB 8

typedef __attribute__((ext_vector_type(8))) short s8v;     // 8 bf16
typedef __attribute__((ext_vector_type(4))) float f4v;
typedef __attribute__((ext_vector_type(16))) float f16v;   // 32x32 acc
typedef __attribute__((ext_vector_type(4))) unsigned u4v;

static __device__ __forceinline__ unsigned pk_bf16(float lo, float hi) {
  __hip_bfloat162 t = __float22bfloat162_rn(float2{lo, hi});
  return *(unsigned*)&t;
}
static __device__ __forceinline__ unsigned short bf16rne(float x) {
  union { float f; unsigned u; } c; c.f = x;
  unsigned r = c.u + 0x7FFFu + ((c.u >> 16) & 1u);
  return (unsigned short)(r >> 16);
}

// ---------------- Kernel 1: Wh/e-factors (blocks 0..511) + adj masks (512..1535) ----------------
__global__ __launch_bounds__(256, 2) void k_pre(
    const float* __restrict__ adj, const float* __restrict__ h,
    const float* __restrict__ W, const float* __restrict__ a,
    unsigned long long* __restrict__ adjq, unsigned short* __restrict__ whswz,
    float2* __restrict__ e1pn, unsigned* __restrict__ e2pk) {
  const int t = threadIdx.x, lane = t & 63, w = t >> 6;

  if (blockIdx.x >= 512) {
    // ---- adj -> bit rows: 2 rows/block, wave -> half row, 16 ballots ----
    const int bid = blockIdx.x - 512;
    const int row = bid * 2 + (w >> 1);
    const int half = w & 1;
    const float* ar = adj + (size_t)row * NN + half * 1024;
    unsigned long long* aq = adjq + row * 32 + half * 16;
    #pragma unroll
    for (int it = 0; it < 16; ++it) {
      unsigned long long m = __ballot(ar[it * 64 + lane] > 0.f);
      if (lane == 0) aq[it] = m;
    }
    return;
  }

  // ---- Wh (bf16, 32x32-B-fragment swizzle) + e-factors; 32 n-rows/block ----
  __shared__ __align__(16) float hs[32][68];
  const int rowBase = blockIdx.x * 32;
  const int b = rowBase >> 11, n0 = rowBase & (NN - 1);

  float wr[64];                                  // W row `lane` (o = lane)
  #pragma unroll
  for (int k = 0; k < 16; ++k)
    *(f4v*)&wr[k * 4] = *(const f4v*)&W[lane * 64 + k * 4];

  #pragma unroll
  for (int qq = 0; qq < 2; ++qq) {
    const int idx = t + 256 * qq;
    const int r = idx >> 4, c = (idx & 15) * 4;
    *(f4v*)&hs[r][c] = *(const f4v*)&h[(size_t)(rowBase + r) * 64 + c];
  }
  const float a1v = a[lane], a2v = a[64 + lane];
  __syncthreads();

  const int r0 = w * 8;                          // 8 n-rows per wave
  float acc[8];
  #pragma unroll
  for (int rr = 0; rr < 8; ++rr) acc[rr] = 0.f;
  #pragma unroll
  for (int f4i = 0; f4i < 16; ++f4i) {
    f4v hv[8];
    #pragma unroll
    for (int rr = 0; rr < 8; ++rr)
      hv[rr] = *(const f4v*)&hs[r0 + rr][f4i * 4];       // lane-uniform broadcast
    #pragma unroll
    for (int x = 0; x < 4; ++x) {
      const float wv = wr[f4i * 4 + x];
      #pragma unroll
      for (int rr = 0; rr < 8; ++rr) acc[rr] = fmaf(hv[rr][x], wv, acc[rr]);
    }
  }

  {  // 32x32 B-frag swizzle store: [b][jc][oh][lane'][8], 16B/thread
    union { s8v v; unsigned u[4]; } cv;
    cv.u[0] = pk_bf16(acc[0], acc[1]);
    cv.u[1] = pk_bf16(acc[2], acc[3]);
    cv.u[2] = pk_bf16(acc[4], acc[5]);
    cv.u[3] = pk_bf16(acc[6], acc[7]);
    const int jc = (n0 + w * 8) >> 4;            // 16-j chunk
    const int oh = lane >> 5;                    // o-half
    const int lp = ((w & 1) << 5) + (lane & 31); // lane' = ksub*32 + n
    unsigned short* dst = whswz + ((size_t)b << 17) + (jc << 10) + (oh << 9) + (lp << 3);
    *(s8v*)dst = cv.v;
  }

  float s1[8], s2[8];
  #pragma unroll
  for (int rr = 0; rr < 8; ++rr) { s1[rr] = acc[rr] * a1v; s2[rr] = acc[rr] * a2v; }
  #pragma unroll
  for (int m = 1; m < 64; m <<= 1)
    #pragma unroll
    for (int rr = 0; rr < 8; ++rr) {
      s1[rr] += __shfl_xor(s1[rr], m);
      s2[rr] += __shfl_xor(s2[rr], m);
    }
  #pragma unroll
  for (int rr = 0; rr < 8; ++rr) {
    if (lane == 0) {
      e1pn[rowBase + rr + r0] = float2{__expf(s1[rr]), __expf(0.2f * s1[rr])};
      e2pk[rowBase + rr + r0] =
          (unsigned)bf16rne(__expf(s2[rr])) |
          ((unsigned)bf16rne(__expf(0.2f * s2[rr])) << 16);
    }
  }
}

// ---------------- Kernel 2: fused attention, 32x32x16 MFMA ----------------
// 512 blocks x 512 thr (8 waves). b = g&7 (XCD-pinned). Block = 32 i-rows.
// Wave w = j-eighth (16 chunks of 16 j). Thread owns A[m=lane&31][k=kh*8+e].
__global__ __launch_bounds__(512, 4) void k_attn(
    const unsigned long long* __restrict__ adjq,
    const unsigned short* __restrict__ whswz,
    const float2* __restrict__ e1png, const unsigned* __restrict__ e2pkg,
    float* __restrict__ out) {
  union SM {
    unsigned e2bf[NN];          //  8 KB packed {E2p,E2n} bf16 per j
    float pc[8][32][68];        // 69.6 KB partial C (aliased; used after loop)
  };
  __shared__ __align__(16) SM sm;
  __shared__ float ls[8][32];

  const int t = threadIdx.x, lane = t & 63, w = t >> 6;
  const int m32 = lane & 31, kh = lane >> 5;
  const int g = blockIdx.x;
  const int b = g & 7;                 // XCD g%8 <-> batch b
  const int i0 = (g >> 3) << 5;
  const size_t bN = (size_t)b * NN;

  // stage packed e2 factors: 512 x u4v = 2048 dwords
  ((u4v*)sm.e2bf)[t] = ((const u4v*)(e2pkg + bN))[t];

  const float2 e1f = e1png[bN + i0 + m32];
  const float E1p = e1f.x, E1n = e1f.y;
  const unsigned long long* arow = adjq + (size_t)(i0 + m32) * 32 + w * 4;
  const unsigned short* wb = whswz + ((size_t)b << 17);

  f16v acc0, acc1;
  #pragma unroll
  for (int r = 0; r < 16; ++r) { acc0[r] = 0.f; acc1[r] = 0.f; }
  float psum = 0.f;

  auto pgen = [&](u4v e0, u4v e1, unsigned bits) -> s8v {
    float p[8];
    #pragma unroll
    for (int e = 0; e < 8; ++e) {
      const unsigned dw = e < 4 ? e0[e] : e1[e - 4];
      const float E2p = __uint_as_float(dw << 16);
      const float E2n = __uint_as_float(dw & 0xffff0000u);
      const float mp = E1p * E2p;          // exp(e1+e2)
      const float mn = E1n * E2n;          // exp(0.2*(e1+e2))
      float pv = mp > 1.f ? mp : mn;       // leaky-relu in exp domain
      pv = ((bits >> e) & 1u) ? pv : 0.f;
      psum += pv;
      p[e] = pv;
    }
    union { s8v v; unsigned u[4]; } cv;
    cv.u[0] = pk_bf16(p[0], p[1]);
    cv.u[1] = pk_bf16(p[2], p[3]);
    cv.u[2] = pk_bf16(p[4], p[5]);
    cv.u[3] = pk_bf16(p[6], p[7]);
    return cv.v;
  };

  __syncthreads();   // e2bf staged

  unsigned long long am = 0;
  #pragma unroll
  for (int it = 0; it < 8; ++it) {
    const int jcl = it * 2;                       // local chunk 0..15
    const int jcA = w * 16 + jcl, jcB = jcA + 1;
    // B-fragments: 4 coalesced 1KB loads
    const s8v bA0 = *(const s8v*)(wb + (jcA << 10) + (lane << 3));
    const s8v bA1 = *(const s8v*)(wb + (jcA << 10) + 512 + (lane << 3));
    const s8v bB0 = *(const s8v*)(wb + (jcB << 10) + (lane << 3));
    const s8v bB1 = *(const s8v*)(wb + (jcB << 10) + 512 + (lane << 3));
    if ((it & 1) == 0) am = arow[it >> 1];        // one 64-j word per 2 iters
    // e2 factor reads (broadcast, 2 distinct addrs/wave)
    const u4v eA0 = *(const u4v*)&sm.e2bf[(jcA << 4) + (kh << 3)];
    const u4v eA1 = *(const u4v*)&sm.e2bf[(jcA << 4) + (kh << 3) + 4];
    const u4v eB0 = *(const u4v*)&sm.e2bf[(jcB << 4) + (kh << 3)];
    const u4v eB1 = *(const u4v*)&sm.e2bf[(jcB << 4) + (kh << 3) + 4];

    const unsigned bitsA = (unsigned)(am >> (((jcl)&3) * 16 + kh * 8)) & 0xffu;
    const unsigned bitsB = (unsigned)(am >> (((jcl + 1) & 3) * 16 + kh * 8)) & 0xffu;
    const s8v afA = pgen(eA0, eA1, bitsA);
    const s8v afB = pgen(eB0, eB1, bitsB);

    acc0 = __builtin_amdgcn_mfma_f32_32x32x16_bf16(afA, bA0, acc0, 0, 0, 0);
    acc1 = __builtin_amdgcn_mfma_f32_32x32x16_bf16(afA, bA1, acc1, 0, 0, 0);
    acc0 = __builtin_amdgcn_mfma_f32_32x32x16_bf16(afB, bB0, acc0, 0, 0, 0);
    acc1 = __builtin_amdgcn_mfma_f32_32x32x16_bf16(afB, bB1, acc1, 0, 0, 0);
  }

  // rowsum: thread's 8 P's/chunk all belong to row m32; merge k-halves
  psum += __shfl_xor(psum, 32);
  __syncthreads();              // all e2bf reads done -> pc alias safe
  if (lane < 32) ls[w][lane] = psum;
  // publish partial C (C/D layout m74/m101: col=lane&31, row=(r&3)+8*(r>>2)+4*kh)
  #pragma unroll
  for (int r = 0; r < 16; ++r) {
    const int row = (r & 3) + 8 * (r >> 2) + 4 * kh;
    sm.pc[w][row][m32] = acc0[r];
    sm.pc[w][row][32 + m32] = acc1[r];
  }
  __syncthreads();

  // gather across 8 waves: thread t -> row t>>4, cols (t&15)*4
  const int row = t >> 4, c0 = (t & 15) * 4;
  f4v sum = *(const f4v*)&sm.pc[0][row][c0];
  #pragma unroll
  for (int j = 1; j < 8; ++j) sum += *(const f4v*)&sm.pc[j][row][c0];
  float rsum = ls[0][row];
  #pragma unroll
  for (int j = 1; j < 8; ++j) rsum += ls[j][row];
  f4v o;
  #pragma unroll
  for (int x = 0; x < 4; ++x) {
    float v = sum[x] / rsum;
    o[x] = v > 0.f ? v : expm1f(v);
  }
  *(f4v*)&out[(bN + i0 + row) * 64 + c0] = o;
}

extern "C" void kernel_launch(void* const* d_in, const int* in_sizes, int n_in,
                              void* d_out, int out_size, void* d_ws, size_t ws_size,
                              hipStream_t stream) {
  (void)in_sizes; (void)n_in; (void)out_size; (void)ws_size;
  const float* h   = (const float*)d_in[0];
  const float* adj = (const float*)d_in[1];
  const float* W   = (const float*)d_in[2];
  const float* a   = (const float*)d_in[3];
  float* outp = (float*)d_out;

  // ws carve: whswz 2 MB | e1pn 128 KB | e2pk 64 KB | adjq 512 KB
  unsigned short* whswz = (unsigned short*)d_ws;
  float2* e1pn = (float2*)((char*)d_ws + (size_t)BB * 64 * NN * 2);
  unsigned* e2pk = (unsigned*)(e1pn + (size_t)BB * NN);
  unsigned long long* adjq = (unsigned long long*)(e2pk + (size_t)BB * NN);

  k_pre<<<1536, 256, 0, stream>>>(adj, h, W, a, adjq, whswz, e1pn, e2pk);
  k_attn<<<512, 512, 0, stream>>>(adjq, whswz, e1pn, e2pk, outp);
}